// Round 11
// baseline (428.892 us; speedup 1.0000x reference)
//
#include <hip/hip_runtime.h>
#include <hip/hip_bf16.h>

// BoostedCausalAttention: bf16 MFMA pipeline
// B=2 T=2048 D=1024 H=16 DH=64, fp32 in/out, bf16 internal compute.
// R6: baseline 589us (attn 213us, 3.35e7 conflicts).
// R8: swizzle+dbuf 475us (attn 153us, conflicts 2.16e6).
// R9: q-tile pairing 352.9us (attn 91.3us, occ 17.9%, VALU 37.8%, Mfma 7.6%).
//   Cap: 512 blocks = 2/CU x 4 waves = 25% occupancy ceiling; hi/lo serial.
// R10: 8-wave blocks (512 thr): waves 0-3 = hi tile, 4-7 = lo tile ->
//   hi/lo concurrent on different SIMDs, 16 waves/CU (50% cap). Same
//   pairing/swizzle/staging; per-wave state halved.
// R11: identical resubmit (infra UnresponsiveContainer; audit clean:
//   uniform barriers, WAR-safe ps overlay, staging coverage verified).

typedef __bf16 bf16x8 __attribute__((ext_vector_type(8)));
typedef float f32x4 __attribute__((ext_vector_type(4)));

__device__ __forceinline__ unsigned short f2bf(float f) {
  union { __hip_bfloat16 h; unsigned short u; } cv;
  cv.h = __float2bfloat16(f);
  return cv.u;
}

#define GLD16(gp, lp) __builtin_amdgcn_global_load_lds(                      \
    (const __attribute__((address_space(1))) void*)(gp),                     \
    (__attribute__((address_space(3))) void*)(lp), 16, 0, 0)

// ---------------- transpose + cast: fp32 [R][C] -> bf16 [C][R] --------------
__global__ __launch_bounds__(256) void transpose_cast(
    const float* __restrict__ in, __hip_bfloat16* __restrict__ out, int R, int C) {
  __shared__ float t[32][33];
  int bx = blockIdx.x * 32, by = blockIdx.y * 32;
  int tx = threadIdx.x, ty = threadIdx.y;
#pragma unroll
  for (int i = 0; i < 32; i += 8)
    t[ty + i][tx] = in[(size_t)(by + ty + i) * C + bx + tx];
  __syncthreads();
#pragma unroll
  for (int i = 0; i < 32; i += 8)
    out[(size_t)(bx + ty + i) * R + by + tx] = __float2bfloat16(t[tx][ty + i]);
}

// ---------------- cast x -> bf16 (vec4) ------------------------------------
__global__ __launch_bounds__(256) void cast_f32_bf16(
    const float* __restrict__ in, __hip_bfloat16* __restrict__ out) {
  size_t e = ((size_t)blockIdx.x * blockDim.x + threadIdx.x) * 4;
  float4 v = *(const float4*)(in + e);
  ushort4 o;
  o.x = f2bf(v.x); o.y = f2bf(v.y); o.z = f2bf(v.z); o.w = f2bf(v.w);
  *(ushort4*)((unsigned short*)out + e) = o;
}

// --- catb[:, :1024] = bf16(pred); residb = bf16(x - pred) -------------------
__global__ __launch_bounds__(256) void resid_cast(
    const float* __restrict__ x, const float* __restrict__ pred,
    __hip_bfloat16* __restrict__ catb, __hip_bfloat16* __restrict__ residb) {
  size_t e = ((size_t)blockIdx.x * blockDim.x + threadIdx.x) * 4;
  float4 xv = *(const float4*)(x + e);
  float4 pv = *(const float4*)(pred + e);
  size_t row = e >> 10, col = e & 1023;
  ushort4 pb, rb;
  pb.x = f2bf(pv.x); pb.y = f2bf(pv.y); pb.z = f2bf(pv.z); pb.w = f2bf(pv.w);
  rb.x = f2bf(xv.x - pv.x); rb.y = f2bf(xv.y - pv.y);
  rb.z = f2bf(xv.z - pv.z); rb.w = f2bf(xv.w - pv.w);
  *(ushort4*)((unsigned short*)catb + row * 2048 + col) = pb;
  *(ushort4*)((unsigned short*)residb + e) = rb;
}

// --- catb[:, 1024:] = bf16(corr) --------------------------------------------
__global__ __launch_bounds__(256) void corr_cast(
    const float* __restrict__ corr, __hip_bfloat16* __restrict__ catb) {
  size_t e = ((size_t)blockIdx.x * blockDim.x + threadIdx.x) * 4;
  float4 v = *(const float4*)(corr + e);
  size_t row = e >> 10, col = e & 1023;
  ushort4 o;
  o.x = f2bf(v.x); o.y = f2bf(v.y); o.z = f2bf(v.z); o.w = f2bf(v.w);
  *(ushort4*)((unsigned short*)catb + row * 2048 + 1024 + col) = o;
}

// ---------------- bf16 MFMA GEMM, 128x128 tile, BK=32 (m97 structure) -------
template <int EPI>
__global__ __launch_bounds__(256) void gemm_bf16(
    const __hip_bfloat16* __restrict__ A, const __hip_bfloat16* __restrict__ Bt,
    const float* __restrict__ bias, void* __restrict__ outp,
    const float* __restrict__ aux0, const float* __restrict__ aux1,
    int M, int N, int K) {
  __shared__ __hip_bfloat16 As[128 * 32];
  __shared__ __hip_bfloat16 Bs[128 * 32];
  const int tid = threadIdx.x;
  const int lane = tid & 63, wid = tid >> 6;
  const int wr = wid >> 1, wc = wid & 1;
  const int lr = lane & 15, lk = (lane >> 4) * 8;
  const size_t brow = (size_t)blockIdx.y * 128, bcol = (size_t)blockIdx.x * 128;
  f32x4 acc[4][4] = {};
  for (int k0 = 0; k0 < K; k0 += 32) {
#pragma unroll
    for (int r = 0; r < 2; ++r) {
      int c = tid + r * 256;  // 512 chunks of 16B per 128x32 tile
      GLD16(A + (brow + (size_t)(c >> 2)) * K + k0 + (c & 3) * 8,
            (__hip_bfloat16*)As + c * 8);
      GLD16(Bt + (bcol + (size_t)(c >> 2)) * K + k0 + (c & 3) * 8,
            (__hip_bfloat16*)Bs + c * 8);
    }
    __syncthreads();
    bf16x8 a[4], b[4];
#pragma unroll
    for (int m = 0; m < 4; ++m)
      a[m] = *(const bf16x8*)(As + (wr * 64 + m * 16 + lr) * 32 + lk);
#pragma unroll
    for (int n = 0; n < 4; ++n)
      b[n] = *(const bf16x8*)(Bs + (wc * 64 + n * 16 + lr) * 32 + lk);
#pragma unroll
    for (int m = 0; m < 4; ++m)
#pragma unroll
      for (int n = 0; n < 4; ++n)
        acc[m][n] = __builtin_amdgcn_mfma_f32_16x16x32_bf16(a[m], b[n], acc[m][n], 0, 0, 0);
    __syncthreads();
  }
  const int r0 = (lane >> 4) * 4, cn = lane & 15;
#pragma unroll
  for (int m = 0; m < 4; ++m)
#pragma unroll
    for (int n = 0; n < 4; ++n) {
      size_t col = bcol + wc * 64 + n * 16 + cn;
      float bv = bias[col];
#pragma unroll
      for (int j = 0; j < 4; ++j) {
        size_t row = brow + wr * 64 + m * 16 + r0 + j;
        float v = acc[m][n][j] + bv;
        if constexpr (EPI == 0) {
          ((__hip_bfloat16*)outp)[row * N + col] = __float2bfloat16(v);
        } else if constexpr (EPI == 1) {
          float g = 1.0f / (1.0f + __expf(-v));
          float val = g * aux0[row * N + col] + aux1[row * N + col];
          ((__hip_bfloat16*)outp)[row * N + col] = __float2bfloat16(val);
        } else {
          ((float*)outp)[row * N + col] = v;
        }
      }
    }
}

// ---------------- causal flash attention V4 (paired tiles, 8 waves) ---------
// Block qtp handles q-tiles qlo=qtp, qhi=31-qtp for one (b,h). 512 threads:
// waves 0-3 own 16-row chunks of the HI tile, waves 4-7 of the LO tile —
// hi/lo run concurrently. KV tiles 0..qhi staged once (dbuf, swizzled).
// Swizzles as R8-verified. LDS 48KB: ks 16K + vts 16K + qps 16K (Q staging
// overlaid by 8x2KB wave-private ps after prologue).
__global__ __launch_bounds__(512) void attn_kernel(
    const __hip_bfloat16* __restrict__ qkv, float* __restrict__ outp) {
  const int b = blockIdx.z, h = blockIdx.y, qtp = blockIdx.x;
  const int qlo = qtp, qhi = 31 - qtp;
  const int q0lo = qlo * 64, q0hi = qhi * 64;
  __shared__ __hip_bfloat16 ks[2][64 * 64];
  __shared__ __hip_bfloat16 vts[2][64 * 64];  // V^T [dh][kv], swizzled
  __shared__ __hip_bfloat16 qps[8192];        // Q_hi|Q_lo staging -> 8x ps
  const int tid = threadIdx.x, lane = tid & 63, w = tid >> 6;
  const bool is_hi = (w < 4);
  const int wrow = (w & 3) * 16;              // row-chunk within own tile
  const int lr = lane & 15, lg = lane >> 4;
  const int sw = lr & 7;
  const size_t rs = 3072;
  const __hip_bfloat16* qbh = qkv + ((size_t)b * 2048 + q0hi) * rs + h * 64;
  const __hip_bfloat16* qbl = qkv + ((size_t)b * 2048 + q0lo) * rs + h * 64;
  const __hip_bfloat16* kb = qkv + (size_t)b * 2048 * rs + 1024 + h * 64;
  const __hip_bfloat16* vb = qkv + (size_t)b * 2048 * rs + 2048 + h * 64;

  float4 vreg;
  // ---- prologue: stage Q_hi/Q_lo/K0 (pre-swizzled src), V0 -> regs
  {
    int c = tid, row = c >> 3, p = c & 7;  // 512 chunks of 16B per tile
    GLD16(qbh + (size_t)row * rs + (p ^ (row & 7)) * 8, qps + c * 8);
    GLD16(qbl + (size_t)row * rs + (p ^ (row & 7)) * 8, qps + 4096 + c * 8);
    GLD16(kb + (size_t)row * rs + (p ^ (row & 7)) * 8, ks[0] + c * 8);
    vreg = *(const float4*)(vb + (size_t)row * rs + p * 8);
  }
  __syncthreads();
  const int qrow = wrow + lr;
  const __hip_bfloat16* qsrc = qps + (is_hi ? 0 : 4096);
  const bf16x8 qa0 = *(const bf16x8*)(qsrc + qrow * 64 + ((lg) ^ (qrow & 7)) * 8);
  const bf16x8 qa1 = *(const bf16x8*)(qsrc + qrow * 64 + ((4 + lg) ^ (qrow & 7)) * 8);
  // write V0 (transpose, swizzled)
  {
    int c = tid, row = c >> 3, seg = c & 7;
    const __hip_bfloat16* e8 = (const __hip_bfloat16*)&vreg;
#pragma unroll
    for (int i = 0; i < 8; ++i)
      vts[0][(seg * 8 + i) * 64 + (((row >> 3) ^ i ^ seg)) * 8 + (row & 7)] = e8[i];
  }
  __syncthreads();  // Q frags in regs; qps now free for ps

  __hip_bfloat16* psw = qps + w * 1024;  // wave-private 2KB
  float m_run[4] = {-1e30f, -1e30f, -1e30f, -1e30f}, l_run[4] = {0, 0, 0, 0};
  f32x4 o[4] = {};
  int cur = 0;
  const int mydiag = is_hi ? qhi : qlo;  // my tile's diagonal kv index

  for (int kvt = 0; kvt <= qhi; ++kvt) {
    const int nxt = cur ^ 1;
    const bool pf = (kvt < qhi);
    if (pf) {  // prefetch next K tile + V rows (512 chunks, 1/thread)
      const int kv1 = (kvt + 1) * 64;
      int c = tid, row = c >> 3, p = c & 7;
      GLD16(kb + (size_t)(kv1 + row) * rs + (p ^ (row & 7)) * 8, ks[nxt] + c * 8);
      vreg = *(const float4*)(vb + (size_t)(kv1 + row) * rs + p * 8);
    }
    if (kvt <= mydiag) {  // my tile still active
      const bool diag = (kvt == mydiag);
      f32x4 s4[4] = {};
#pragma unroll
      for (int n = 0; n < 4; ++n) {
        const int kr = n * 16 + lr;
        bf16x8 k0f = *(const bf16x8*)(ks[cur] + kr * 64 + ((lg) ^ sw) * 8);
        bf16x8 k1f = *(const bf16x8*)(ks[cur] + kr * 64 + ((4 + lg) ^ sw) * 8);
        s4[n] = __builtin_amdgcn_mfma_f32_16x16x32_bf16(qa0, k0f, s4[n], 0, 0, 0);
        s4[n] = __builtin_amdgcn_mfma_f32_16x16x32_bf16(qa1, k1f, s4[n], 0, 0, 0);
      }
      float p[4][4], mloc[4];
#pragma unroll
      for (int j = 0; j < 4; ++j) {
        float mm = -1e30f;
#pragma unroll
        for (int n = 0; n < 4; ++n) {
          float v = s4[n][j] * 0.125f;
          if (diag && (n * 16 + lr) > (wrow + lg * 4 + j)) v = -1e30f;
          p[n][j] = v;
          mm = fmaxf(mm, v);
        }
        mloc[j] = mm;
      }
#pragma unroll
      for (int off = 1; off < 16; off <<= 1)
#pragma unroll
        for (int j = 0; j < 4; ++j)
          mloc[j] = fmaxf(mloc[j], __shfl_xor(mloc[j], off, 16));
      float sc[4], ls[4];
#pragma unroll
      for (int j = 0; j < 4; ++j) {
        float mn = fmaxf(m_run[j], mloc[j]);
        sc[j] = __expf(m_run[j] - mn);
        m_run[j] = mn;
        float s = 0.f;
#pragma unroll
        for (int n = 0; n < 4; ++n) { p[n][j] = __expf(p[n][j] - mn); s += p[n][j]; }
        ls[j] = s;
      }
#pragma unroll
      for (int off = 1; off < 16; off <<= 1)
#pragma unroll
        for (int j = 0; j < 4; ++j) ls[j] += __shfl_xor(ls[j], off, 16);
#pragma unroll
      for (int j = 0; j < 4; ++j) l_run[j] = l_run[j] * sc[j] + ls[j];
#pragma unroll
      for (int n = 0; n < 4; ++n)
#pragma unroll
        for (int j = 0; j < 4; ++j) o[n][j] *= sc[j];
      // P (C-layout) -> wave-private swizzled LDS -> A-operand layout
#pragma unroll
      for (int n = 0; n < 4; ++n)
#pragma unroll
        for (int j = 0; j < 4; ++j) {
          const int prow = lg * 4 + j;
          const int phys = (n * 2 + (lr >> 3)) ^ (prow & 7);
          psw[prow * 64 + phys * 8 + (lr & 7)] = __float2bfloat16(p[n][j]);
        }
      bf16x8 pa0 = *(const bf16x8*)(&psw[lr * 64 + ((lg) ^ sw) * 8]);
      bf16x8 pa1 = *(const bf16x8*)(&psw[lr * 64 + ((4 + lg) ^ sw) * 8]);
#pragma unroll
      for (int n = 0; n < 4; ++n) {
        const int vdh = n * 16 + lr;
        const int swv = (vdh & 7) ^ ((vdh >> 3) & 7);
        bf16x8 v0f = *(const bf16x8*)(vts[cur] + vdh * 64 + ((lg) ^ swv) * 8);
        bf16x8 v1f = *(const bf16x8*)(vts[cur] + vdh * 64 + ((4 + lg) ^ swv) * 8);
        o[n] = __builtin_amdgcn_mfma_f32_16x16x32_bf16(pa0, v0f, o[n], 0, 0, 0);
        o[n] = __builtin_amdgcn_mfma_f32_16x16x32_bf16(pa1, v1f, o[n], 0, 0, 0);
      }
    }
    if (pf) {  // write V(t+1) regs -> vts[nxt] (vmcnt wait after compute)
      int c = tid, row = c >> 3, seg = c & 7;
      const __hip_bfloat16* e8 = (const __hip_bfloat16*)&vreg;
#pragma unroll
      for (int i = 0; i < 8; ++i)
        vts[nxt][(seg * 8 + i) * 64 + (((row >> 3) ^ i ^ seg)) * 8 + (row & 7)] = e8[i];
    }
    __syncthreads();
    cur = nxt;
  }
  const int q0 = is_hi ? q0hi : q0lo;
#pragma unroll
  for (int j = 0; j < 4; ++j) {
    float inv = 1.0f / l_run[j];
    size_t row = (size_t)b * 2048 + q0 + wrow + lg * 4 + j;
#pragma unroll
    for (int n = 0; n < 4; ++n)
      outp[row * 1024 + h * 64 + n * 16 + lr] = o[n][j] * inv;
  }
}

extern "C" void kernel_launch(void* const* d_in, const int* in_sizes, int n_in,
                              void* d_out, int out_size, void* d_ws, size_t ws_size,
                              hipStream_t stream) {
  const float* x     = (const float*)d_in[0];
  const float* Wqkv0 = (const float*)d_in[1];
  const float* bqkv0 = (const float*)d_in[2];
  const float* Wqkv1 = (const float*)d_in[3];
  const float* bqkv1 = (const float*)d_in[4];
  const float* Wg    = (const float*)d_in[5];
  const float* bg    = (const float*)d_in[6];
  const float* Wo    = (const float*)d_in[7];
  const float* bo    = (const float*)d_in[8];
  float* out = (float*)d_out;

  char* ws = (char*)d_ws;
  __hip_bfloat16* xb   = (__hip_bfloat16*)(ws);              // 8 MB (x_bf16 -> residb -> preout)
  __hip_bfloat16* qkv  = (__hip_bfloat16*)(ws + 8388608);    // 24 MB (qkv0 then qkv1)
  float*          pred = (float*)(ws + 33554432);            // 16 MB
  float*          corr = (float*)(ws + 50331648);            // 16 MB
  __hip_bfloat16* catb = (__hip_bfloat16*)(ws + 67108864);   // 16 MB [pred | corr] bf16
  __hip_bfloat16* Wt0  = (__hip_bfloat16*)(ws + 83886080);   // 6 MB
  __hip_bfloat16* Wt1  = (__hip_bfloat16*)(ws + 90177536);   // 6 MB
  __hip_bfloat16* Wgt  = (__hip_bfloat16*)(ws + 96468992);   // 4 MB
  __hip_bfloat16* Wot  = (__hip_bfloat16*)(ws + 100663296);  // 2 MB  (total ~98 MB)

  dim3 tb(32, 8);
  transpose_cast<<<dim3(3072 / 32, 1024 / 32), tb, 0, stream>>>(Wqkv0, Wt0, 1024, 3072);
  transpose_cast<<<dim3(3072 / 32, 1024 / 32), tb, 0, stream>>>(Wqkv1, Wt1, 1024, 3072);
  transpose_cast<<<dim3(1024 / 32, 2048 / 32), tb, 0, stream>>>(Wg, Wgt, 2048, 1024);
  transpose_cast<<<dim3(1024 / 32, 1024 / 32), tb, 0, stream>>>(Wo, Wot, 1024, 1024);
  cast_f32_bf16<<<4096, 256, 0, stream>>>(x, xb);

  // qkv0 = x @ Wqkv0 + b
  gemm_bf16<0><<<dim3(24, 32), 256, 0, stream>>>(xb, Wt0, bqkv0, (void*)qkv,
                                                 nullptr, nullptr, 4096, 3072, 1024);
  attn_kernel<<<dim3(16, 16, 2), 512, 0, stream>>>(qkv, pred);
  resid_cast<<<4096, 256, 0, stream>>>(x, pred, catb, xb);
  // qkv1 = (x - pred) @ Wqkv1 + b
  gemm_bf16<0><<<dim3(24, 32), 256, 0, stream>>>(xb, Wt1, bqkv1, (void*)qkv,
                                                 nullptr, nullptr, 4096, 3072, 1024);
  attn_kernel<<<dim3(16, 16, 2), 512, 0, stream>>>(qkv, corr);
  corr_cast<<<4096, 256, 0, stream>>>(corr, catb);
  // preout = sigmoid(cat @ Wg + bg) * corr + pred   (into xb)
  gemm_bf16<1><<<dim3(8, 32), 256, 0, stream>>>(catb, Wgt, bg, (void*)xb,
                                                corr, pred, 4096, 1024, 2048);
  // out = preout @ Wo + bo (fp32)
  gemm_bf16<2><<<dim3(8, 32), 256, 0, stream>>>(xb, Wot, bo, (void*)out,
                                                nullptr, nullptr, 4096, 1024, 1024);
}

// Round 12
// 389.657 us; speedup vs baseline: 1.1007x; 1.1007x over previous
//
#include <hip/hip_runtime.h>
#include <hip/hip_bf16.h>

// BoostedCausalAttention: bf16 MFMA pipeline
// B=2 T=2048 D=1024 H=16 DH=64, fp32 in/out, bf16 internal compute.
// R6: baseline 589us (attn 213us, 3.35e7 conflicts).
// R8: swizzle+dbuf 475us (attn 153us, conflicts 2.16e6).
// R9 (verified): q-tile pairing 352.9us (attn 91.3us, VALU 37.8%, Mfma 7.6%).
// R11 (REGRESSION, reverted): 8-wave split 428.9us — halved compute-per-
//   barrier re-exposed HBM latency + lo-wave idling. Lesson: compute per
//   barrier is the latency-hiding currency.
// R12: R9 structure + XCD-aware dispatch swizzle: all 16 qtp-blocks of one
//   (b,h) land on one XCD (4 groups/XCD = 2MB KV fits 4MB L2) -> K/V
//   prefetch becomes L2-hit (~200cyc < ~400cyc compute) on the majority
//   1-process iterations.

typedef __bf16 bf16x8 __attribute__((ext_vector_type(8)));
typedef float f32x4 __attribute__((ext_vector_type(4)));

__device__ __forceinline__ unsigned short f2bf(float f) {
  union { __hip_bfloat16 h; unsigned short u; } cv;
  cv.h = __float2bfloat16(f);
  return cv.u;
}

#define GLD16(gp, lp) __builtin_amdgcn_global_load_lds(                      \
    (const __attribute__((address_space(1))) void*)(gp),                     \
    (__attribute__((address_space(3))) void*)(lp), 16, 0, 0)

// ---------------- transpose + cast: fp32 [R][C] -> bf16 [C][R] --------------
__global__ __launch_bounds__(256) void transpose_cast(
    const float* __restrict__ in, __hip_bfloat16* __restrict__ out, int R, int C) {
  __shared__ float t[32][33];
  int bx = blockIdx.x * 32, by = blockIdx.y * 32;
  int tx = threadIdx.x, ty = threadIdx.y;
#pragma unroll
  for (int i = 0; i < 32; i += 8)
    t[ty + i][tx] = in[(size_t)(by + ty + i) * C + bx + tx];
  __syncthreads();
#pragma unroll
  for (int i = 0; i < 32; i += 8)
    out[(size_t)(bx + ty + i) * R + by + tx] = __float2bfloat16(t[tx][ty + i]);
}

// ---------------- cast x -> bf16 (vec4) ------------------------------------
__global__ __launch_bounds__(256) void cast_f32_bf16(
    const float* __restrict__ in, __hip_bfloat16* __restrict__ out) {
  size_t e = ((size_t)blockIdx.x * blockDim.x + threadIdx.x) * 4;
  float4 v = *(const float4*)(in + e);
  ushort4 o;
  o.x = f2bf(v.x); o.y = f2bf(v.y); o.z = f2bf(v.z); o.w = f2bf(v.w);
  *(ushort4*)((unsigned short*)out + e) = o;
}

// --- catb[:, :1024] = bf16(pred); residb = bf16(x - pred) -------------------
__global__ __launch_bounds__(256) void resid_cast(
    const float* __restrict__ x, const float* __restrict__ pred,
    __hip_bfloat16* __restrict__ catb, __hip_bfloat16* __restrict__ residb) {
  size_t e = ((size_t)blockIdx.x * blockDim.x + threadIdx.x) * 4;
  float4 xv = *(const float4*)(x + e);
  float4 pv = *(const float4*)(pred + e);
  size_t row = e >> 10, col = e & 1023;
  ushort4 pb, rb;
  pb.x = f2bf(pv.x); pb.y = f2bf(pv.y); pb.z = f2bf(pv.z); pb.w = f2bf(pv.w);
  rb.x = f2bf(xv.x - pv.x); rb.y = f2bf(xv.y - pv.y);
  rb.z = f2bf(xv.z - pv.z); rb.w = f2bf(xv.w - pv.w);
  *(ushort4*)((unsigned short*)catb + row * 2048 + col) = pb;
  *(ushort4*)((unsigned short*)residb + e) = rb;
}

// --- catb[:, 1024:] = bf16(corr) --------------------------------------------
__global__ __launch_bounds__(256) void corr_cast(
    const float* __restrict__ corr, __hip_bfloat16* __restrict__ catb) {
  size_t e = ((size_t)blockIdx.x * blockDim.x + threadIdx.x) * 4;
  float4 v = *(const float4*)(corr + e);
  size_t row = e >> 10, col = e & 1023;
  ushort4 o;
  o.x = f2bf(v.x); o.y = f2bf(v.y); o.z = f2bf(v.z); o.w = f2bf(v.w);
  *(ushort4*)((unsigned short*)catb + row * 2048 + 1024 + col) = o;
}

// ---------------- bf16 MFMA GEMM, 128x128 tile, BK=32 (m97 structure) -------
template <int EPI>
__global__ __launch_bounds__(256) void gemm_bf16(
    const __hip_bfloat16* __restrict__ A, const __hip_bfloat16* __restrict__ Bt,
    const float* __restrict__ bias, void* __restrict__ outp,
    const float* __restrict__ aux0, const float* __restrict__ aux1,
    int M, int N, int K) {
  __shared__ __hip_bfloat16 As[128 * 32];
  __shared__ __hip_bfloat16 Bs[128 * 32];
  const int tid = threadIdx.x;
  const int lane = tid & 63, wid = tid >> 6;
  const int wr = wid >> 1, wc = wid & 1;
  const int lr = lane & 15, lk = (lane >> 4) * 8;
  const size_t brow = (size_t)blockIdx.y * 128, bcol = (size_t)blockIdx.x * 128;
  f32x4 acc[4][4] = {};
  for (int k0 = 0; k0 < K; k0 += 32) {
#pragma unroll
    for (int r = 0; r < 2; ++r) {
      int c = tid + r * 256;  // 512 chunks of 16B per 128x32 tile
      GLD16(A + (brow + (size_t)(c >> 2)) * K + k0 + (c & 3) * 8,
            (__hip_bfloat16*)As + c * 8);
      GLD16(Bt + (bcol + (size_t)(c >> 2)) * K + k0 + (c & 3) * 8,
            (__hip_bfloat16*)Bs + c * 8);
    }
    __syncthreads();
    bf16x8 a[4], b[4];
#pragma unroll
    for (int m = 0; m < 4; ++m)
      a[m] = *(const bf16x8*)(As + (wr * 64 + m * 16 + lr) * 32 + lk);
#pragma unroll
    for (int n = 0; n < 4; ++n)
      b[n] = *(const bf16x8*)(Bs + (wc * 64 + n * 16 + lr) * 32 + lk);
#pragma unroll
    for (int m = 0; m < 4; ++m)
#pragma unroll
      for (int n = 0; n < 4; ++n)
        acc[m][n] = __builtin_amdgcn_mfma_f32_16x16x32_bf16(a[m], b[n], acc[m][n], 0, 0, 0);
    __syncthreads();
  }
  const int r0 = (lane >> 4) * 4, cn = lane & 15;
#pragma unroll
  for (int m = 0; m < 4; ++m)
#pragma unroll
    for (int n = 0; n < 4; ++n) {
      size_t col = bcol + wc * 64 + n * 16 + cn;
      float bv = bias[col];
#pragma unroll
      for (int j = 0; j < 4; ++j) {
        size_t row = brow + wr * 64 + m * 16 + r0 + j;
        float v = acc[m][n][j] + bv;
        if constexpr (EPI == 0) {
          ((__hip_bfloat16*)outp)[row * N + col] = __float2bfloat16(v);
        } else if constexpr (EPI == 1) {
          float g = 1.0f / (1.0f + __expf(-v));
          float val = g * aux0[row * N + col] + aux1[row * N + col];
          ((__hip_bfloat16*)outp)[row * N + col] = __float2bfloat16(val);
        } else {
          ((float*)outp)[row * N + col] = v;
        }
      }
    }
}

// ---------------- causal flash attention V3x (paired q-tiles, XCD swizzle) --
// R9-verified structure. 1-D grid of 512; dispatch id L decodes so all 16
// qtp-blocks of one (b,h) land on the same XCD (L%8 = const for the group):
//   g_lo=L&7, qtp=(L>>3)&15, g_hi=L>>7, g=g_hi*8+g_lo, h=g&15, b=g>>4.
// Block handles q-tiles qlo=qtp, qhi=31-qtp. 4 waves; wave w owns rows
// [w*16,w*16+16) of BOTH tiles. KV tiles 0..qhi staged once (dbuf, swizzled).
// Swizzles as R8-verified. LDS 48KB: ks 16K + vts 16K + qps 16K (Q staging
// overlaid by ps after prologue).
__global__ __launch_bounds__(256) void attn_kernel(
    const __hip_bfloat16* __restrict__ qkv, float* __restrict__ outp) {
  const int L = blockIdx.x;
  const int g = (L >> 7) * 8 + (L & 7);  // (b,h) group, XCD-resident
  const int qtp = (L >> 3) & 15;
  const int h = g & 15, b = g >> 4;
  const int qlo = qtp, qhi = 31 - qtp;
  const int q0lo = qlo * 64, q0hi = qhi * 64;
  __shared__ __hip_bfloat16 ks[2][64 * 64];
  __shared__ __hip_bfloat16 vts[2][64 * 64];  // V^T [dh][kv], swizzled
  __shared__ __hip_bfloat16 qps[8192];        // Q_hi|Q_lo staging -> ps_hi|ps_lo
  const int tid = threadIdx.x, lane = tid & 63, w = tid >> 6;
  const int lr = lane & 15, lg = lane >> 4;
  const int sw = lr & 7;
  const size_t rs = 3072;
  const __hip_bfloat16* qbh = qkv + ((size_t)b * 2048 + q0hi) * rs + h * 64;
  const __hip_bfloat16* qbl = qkv + ((size_t)b * 2048 + q0lo) * rs + h * 64;
  const __hip_bfloat16* kb = qkv + (size_t)b * 2048 * rs + 1024 + h * 64;
  const __hip_bfloat16* vb = qkv + (size_t)b * 2048 * rs + 2048 + h * 64;

  float4 vreg[2];
  // ---- prologue: stage Q_hi/Q_lo/K0 (pre-swizzled src), V0 -> regs
#pragma unroll
  for (int r = 0; r < 2; ++r) {
    int c = tid + r * 256, row = c >> 3, p = c & 7;
    GLD16(qbh + (size_t)row * rs + (p ^ (row & 7)) * 8, qps + c * 8);
    GLD16(qbl + (size_t)row * rs + (p ^ (row & 7)) * 8, qps + 4096 + c * 8);
    GLD16(kb + (size_t)row * rs + (p ^ (row & 7)) * 8, ks[0] + c * 8);
    vreg[r] = *(const float4*)(vb + (size_t)row * rs + p * 8);
  }
  __syncthreads();
  const int qrow = w * 16 + lr;
  const bf16x8 qh0 = *(const bf16x8*)(qps + qrow * 64 + ((lg) ^ (qrow & 7)) * 8);
  const bf16x8 qh1 = *(const bf16x8*)(qps + qrow * 64 + ((4 + lg) ^ (qrow & 7)) * 8);
  const bf16x8 ql0 = *(const bf16x8*)(qps + 4096 + qrow * 64 + ((lg) ^ (qrow & 7)) * 8);
  const bf16x8 ql1 = *(const bf16x8*)(qps + 4096 + qrow * 64 + ((4 + lg) ^ (qrow & 7)) * 8);
  // write V0 (transpose, swizzled)
#pragma unroll
  for (int r = 0; r < 2; ++r) {
    int c = tid + r * 256, row = c >> 3, seg = c & 7;
    const __hip_bfloat16* e8 = (const __hip_bfloat16*)&vreg[r];
#pragma unroll
    for (int i = 0; i < 8; ++i)
      vts[0][(seg * 8 + i) * 64 + (((row >> 3) ^ i ^ seg)) * 8 + (row & 7)] = e8[i];
  }
  __syncthreads();  // Q frags in regs (drained above); qps now free for ps

  __hip_bfloat16* psh = qps + w * 1024;         // wave-private, hi tile
  __hip_bfloat16* psl = qps + 4096 + w * 1024;  // wave-private, lo tile
  float m_hi[4] = {-1e30f, -1e30f, -1e30f, -1e30f}, l_hi[4] = {0, 0, 0, 0};
  float m_lo[4] = {-1e30f, -1e30f, -1e30f, -1e30f}, l_lo[4] = {0, 0, 0, 0};
  f32x4 o_hi[4] = {}, o_lo[4] = {};
  int cur = 0;

  // one q-tile update against ks[cur]/vts[cur]
  auto process = [&](const bf16x8& qa0, const bf16x8& qa1, bool diag,
                     float* m_run, float* l_run, f32x4* o, __hip_bfloat16* psw) {
    f32x4 s4[4] = {};
#pragma unroll
    for (int n = 0; n < 4; ++n) {
      const int kr = n * 16 + lr;
      bf16x8 k0f = *(const bf16x8*)(ks[cur] + kr * 64 + ((lg) ^ sw) * 8);
      bf16x8 k1f = *(const bf16x8*)(ks[cur] + kr * 64 + ((4 + lg) ^ sw) * 8);
      s4[n] = __builtin_amdgcn_mfma_f32_16x16x32_bf16(qa0, k0f, s4[n], 0, 0, 0);
      s4[n] = __builtin_amdgcn_mfma_f32_16x16x32_bf16(qa1, k1f, s4[n], 0, 0, 0);
    }
    float p[4][4], mloc[4];
#pragma unroll
    for (int j = 0; j < 4; ++j) {
      float mm = -1e30f;
#pragma unroll
      for (int n = 0; n < 4; ++n) {
        float v = s4[n][j] * 0.125f;
        if (diag && (n * 16 + lr) > (w * 16 + lg * 4 + j)) v = -1e30f;
        p[n][j] = v;
        mm = fmaxf(mm, v);
      }
      mloc[j] = mm;
    }
#pragma unroll
    for (int off = 1; off < 16; off <<= 1)
#pragma unroll
      for (int j = 0; j < 4; ++j)
        mloc[j] = fmaxf(mloc[j], __shfl_xor(mloc[j], off, 16));
    float sc[4], ls[4];
#pragma unroll
    for (int j = 0; j < 4; ++j) {
      float mn = fmaxf(m_run[j], mloc[j]);
      sc[j] = __expf(m_run[j] - mn);
      m_run[j] = mn;
      float s = 0.f;
#pragma unroll
      for (int n = 0; n < 4; ++n) { p[n][j] = __expf(p[n][j] - mn); s += p[n][j]; }
      ls[j] = s;
    }
#pragma unroll
    for (int off = 1; off < 16; off <<= 1)
#pragma unroll
      for (int j = 0; j < 4; ++j) ls[j] += __shfl_xor(ls[j], off, 16);
#pragma unroll
    for (int j = 0; j < 4; ++j) l_run[j] = l_run[j] * sc[j] + ls[j];
#pragma unroll
    for (int n = 0; n < 4; ++n)
#pragma unroll
      for (int j = 0; j < 4; ++j) o[n][j] *= sc[j];
#pragma unroll
    for (int n = 0; n < 4; ++n)
#pragma unroll
      for (int j = 0; j < 4; ++j) {
        const int prow = lg * 4 + j;
        const int phys = (n * 2 + (lr >> 3)) ^ (prow & 7);
        psw[prow * 64 + phys * 8 + (lr & 7)] = __float2bfloat16(p[n][j]);
      }
    bf16x8 pa0 = *(const bf16x8*)(&psw[lr * 64 + ((lg) ^ sw) * 8]);
    bf16x8 pa1 = *(const bf16x8*)(&psw[lr * 64 + ((4 + lg) ^ sw) * 8]);
#pragma unroll
    for (int n = 0; n < 4; ++n) {
      const int vdh = n * 16 + lr;
      const int swv = (vdh & 7) ^ ((vdh >> 3) & 7);
      bf16x8 v0f = *(const bf16x8*)(vts[cur] + vdh * 64 + ((lg) ^ swv) * 8);
      bf16x8 v1f = *(const bf16x8*)(vts[cur] + vdh * 64 + ((4 + lg) ^ swv) * 8);
      o[n] = __builtin_amdgcn_mfma_f32_16x16x32_bf16(pa0, v0f, o[n], 0, 0, 0);
      o[n] = __builtin_amdgcn_mfma_f32_16x16x32_bf16(pa1, v1f, o[n], 0, 0, 0);
    }
  };

  for (int kvt = 0; kvt <= qhi; ++kvt) {
    const int nxt = cur ^ 1;
    const bool pf = (kvt < qhi);
    if (pf) {  // prefetch next K tile + V rows
      const int kv1 = (kvt + 1) * 64;
#pragma unroll
      for (int r = 0; r < 2; ++r) {
        int c = tid + r * 256, row = c >> 3, p = c & 7;
        GLD16(kb + (size_t)(kv1 + row) * rs + (p ^ (row & 7)) * 8, ks[nxt] + c * 8);
        vreg[r] = *(const float4*)(vb + (size_t)(kv1 + row) * rs + p * 8);
      }
    }
    process(qh0, qh1, kvt == qhi, m_hi, l_hi, o_hi, psh);
    if (kvt <= qlo) process(ql0, ql1, kvt == qlo, m_lo, l_lo, o_lo, psl);
    if (pf) {  // write V(t+1) regs -> vts[nxt] (vmcnt wait after compute)
#pragma unroll
      for (int r = 0; r < 2; ++r) {
        int c = tid + r * 256, row = c >> 3, seg = c & 7;
        const __hip_bfloat16* e8 = (const __hip_bfloat16*)&vreg[r];
#pragma unroll
        for (int i = 0; i < 8; ++i)
          vts[nxt][(seg * 8 + i) * 64 + (((row >> 3) ^ i ^ seg)) * 8 + (row & 7)] = e8[i];
      }
    }
    __syncthreads();
    cur = nxt;
  }
#pragma unroll
  for (int j = 0; j < 4; ++j) {
    float invh = 1.0f / l_hi[j], invl = 1.0f / l_lo[j];
    size_t rowh = (size_t)b * 2048 + q0hi + w * 16 + lg * 4 + j;
    size_t rowl = (size_t)b * 2048 + q0lo + w * 16 + lg * 4 + j;
#pragma unroll
    for (int n = 0; n < 4; ++n) {
      outp[rowh * 1024 + h * 64 + n * 16 + lr] = o_hi[n][j] * invh;
      outp[rowl * 1024 + h * 64 + n * 16 + lr] = o_lo[n][j] * invl;
    }
  }
}

extern "C" void kernel_launch(void* const* d_in, const int* in_sizes, int n_in,
                              void* d_out, int out_size, void* d_ws, size_t ws_size,
                              hipStream_t stream) {
  const float* x     = (const float*)d_in[0];
  const float* Wqkv0 = (const float*)d_in[1];
  const float* bqkv0 = (const float*)d_in[2];
  const float* Wqkv1 = (const float*)d_in[3];
  const float* bqkv1 = (const float*)d_in[4];
  const float* Wg    = (const float*)d_in[5];
  const float* bg    = (const float*)d_in[6];
  const float* Wo    = (const float*)d_in[7];
  const float* bo    = (const float*)d_in[8];
  float* out = (float*)d_out;

  char* ws = (char*)d_ws;
  __hip_bfloat16* xb   = (__hip_bfloat16*)(ws);              // 8 MB (x_bf16 -> residb -> preout)
  __hip_bfloat16* qkv  = (__hip_bfloat16*)(ws + 8388608);    // 24 MB (qkv0 then qkv1)
  float*          pred = (float*)(ws + 33554432);            // 16 MB
  float*          corr = (float*)(ws + 50331648);            // 16 MB
  __hip_bfloat16* catb = (__hip_bfloat16*)(ws + 67108864);   // 16 MB [pred | corr] bf16
  __hip_bfloat16* Wt0  = (__hip_bfloat16*)(ws + 83886080);   // 6 MB
  __hip_bfloat16* Wt1  = (__hip_bfloat16*)(ws + 90177536);   // 6 MB
  __hip_bfloat16* Wgt  = (__hip_bfloat16*)(ws + 96468992);   // 4 MB
  __hip_bfloat16* Wot  = (__hip_bfloat16*)(ws + 100663296);  // 2 MB  (total ~98 MB)

  dim3 tb(32, 8);
  transpose_cast<<<dim3(3072 / 32, 1024 / 32), tb, 0, stream>>>(Wqkv0, Wt0, 1024, 3072);
  transpose_cast<<<dim3(3072 / 32, 1024 / 32), tb, 0, stream>>>(Wqkv1, Wt1, 1024, 3072);
  transpose_cast<<<dim3(1024 / 32, 2048 / 32), tb, 0, stream>>>(Wg, Wgt, 2048, 1024);
  transpose_cast<<<dim3(1024 / 32, 1024 / 32), tb, 0, stream>>>(Wo, Wot, 1024, 1024);
  cast_f32_bf16<<<4096, 256, 0, stream>>>(x, xb);

  // qkv0 = x @ Wqkv0 + b
  gemm_bf16<0><<<dim3(24, 32), 256, 0, stream>>>(xb, Wt0, bqkv0, (void*)qkv,
                                                 nullptr, nullptr, 4096, 3072, 1024);
  attn_kernel<<<512, 256, 0, stream>>>(qkv, pred);
  resid_cast<<<4096, 256, 0, stream>>>(x, pred, catb, xb);
  // qkv1 = (x - pred) @ Wqkv1 + b
  gemm_bf16<0><<<dim3(24, 32), 256, 0, stream>>>(xb, Wt1, bqkv1, (void*)qkv,
                                                 nullptr, nullptr, 4096, 3072, 1024);
  attn_kernel<<<512, 256, 0, stream>>>(qkv, corr);
  corr_cast<<<4096, 256, 0, stream>>>(corr, catb);
  // preout = sigmoid(cat @ Wg + bg) * corr + pred   (into xb)
  gemm_bf16<1><<<dim3(8, 32), 256, 0, stream>>>(catb, Wgt, bg, (void*)xb,
                                                corr, pred, 4096, 1024, 2048);
  // out = preout @ Wo + bo (fp32)
  gemm_bf16<2><<<dim3(8, 32), 256, 0, stream>>>(xb, Wot, bo, (void*)out,
                                                nullptr, nullptr, 4096, 1024, 1024);
}

// Round 14
// 354.138 us; speedup vs baseline: 1.2111x; 1.1003x over previous
//
#include <hip/hip_runtime.h>
#include <hip/hip_bf16.h>

// BoostedCausalAttention: bf16 MFMA pipeline
// B=2 T=2048 D=1024 H=16 DH=64, fp32 in/out, bf16 internal compute.
// R6: baseline 589us. R8: swizzle+dbuf 475us. R9 (verified): pairing 352.9us
//   (attn 91.3us). R11 (reverted): 8-wave split regressed. R12 (reverted):
//   XCD pinning: FETCH 5x down but dur up — attn NOT HBM/latency-bound.
// DS-pipe model (R12 post-mortem): 288 b128 + 384 b16 DS ops/CU-iter ~ 5700
//   cyc = measured ~6850 cyc/iter -> LDS pipe is the saturated resource.
// R13: (a) attn V3i — merged hi/lo body: K/V fragments read ONCE for both
//   tiles (b128 reads 36->20 per wave-iter, -27% DS); XCD decode reverted.
//   (b) all GEMMs double-buffered: stage t+1 before compute t, 1 barrier/iter.
// R14: identical resubmit (infra UnresponsiveContainer; offline audit clean:
//   block-uniform lo_act guard, WAR-free dbuf, VGPR headroom OK).

typedef __bf16 bf16x8 __attribute__((ext_vector_type(8)));
typedef float f32x4 __attribute__((ext_vector_type(4)));

__device__ __forceinline__ unsigned short f2bf(float f) {
  union { __hip_bfloat16 h; unsigned short u; } cv;
  cv.h = __float2bfloat16(f);
  return cv.u;
}

#define GLD16(gp, lp) __builtin_amdgcn_global_load_lds(                      \
    (const __attribute__((address_space(1))) void*)(gp),                     \
    (__attribute__((address_space(3))) void*)(lp), 16, 0, 0)

// ---------------- transpose + cast: fp32 [R][C] -> bf16 [C][R] --------------
__global__ __launch_bounds__(256) void transpose_cast(
    const float* __restrict__ in, __hip_bfloat16* __restrict__ out, int R, int C) {
  __shared__ float t[32][33];
  int bx = blockIdx.x * 32, by = blockIdx.y * 32;
  int tx = threadIdx.x, ty = threadIdx.y;
#pragma unroll
  for (int i = 0; i < 32; i += 8)
    t[ty + i][tx] = in[(size_t)(by + ty + i) * C + bx + tx];
  __syncthreads();
#pragma unroll
  for (int i = 0; i < 32; i += 8)
    out[(size_t)(bx + ty + i) * R + by + tx] = __float2bfloat16(t[tx][ty + i]);
}

// ---------------- cast x -> bf16 (vec4) ------------------------------------
__global__ __launch_bounds__(256) void cast_f32_bf16(
    const float* __restrict__ in, __hip_bfloat16* __restrict__ out) {
  size_t e = ((size_t)blockIdx.x * blockDim.x + threadIdx.x) * 4;
  float4 v = *(const float4*)(in + e);
  ushort4 o;
  o.x = f2bf(v.x); o.y = f2bf(v.y); o.z = f2bf(v.z); o.w = f2bf(v.w);
  *(ushort4*)((unsigned short*)out + e) = o;
}

// --- catb[:, :1024] = bf16(pred); residb = bf16(x - pred) -------------------
__global__ __launch_bounds__(256) void resid_cast(
    const float* __restrict__ x, const float* __restrict__ pred,
    __hip_bfloat16* __restrict__ catb, __hip_bfloat16* __restrict__ residb) {
  size_t e = ((size_t)blockIdx.x * blockDim.x + threadIdx.x) * 4;
  float4 xv = *(const float4*)(x + e);
  float4 pv = *(const float4*)(pred + e);
  size_t row = e >> 10, col = e & 1023;
  ushort4 pb, rb;
  pb.x = f2bf(pv.x); pb.y = f2bf(pv.y); pb.z = f2bf(pv.z); pb.w = f2bf(pv.w);
  rb.x = f2bf(xv.x - pv.x); rb.y = f2bf(xv.y - pv.y);
  rb.z = f2bf(xv.z - pv.z); rb.w = f2bf(xv.w - pv.w);
  *(ushort4*)((unsigned short*)catb + row * 2048 + col) = pb;
  *(ushort4*)((unsigned short*)residb + e) = rb;
}

// --- catb[:, 1024:] = bf16(corr) --------------------------------------------
__global__ __launch_bounds__(256) void corr_cast(
    const float* __restrict__ corr, __hip_bfloat16* __restrict__ catb) {
  size_t e = ((size_t)blockIdx.x * blockDim.x + threadIdx.x) * 4;
  float4 v = *(const float4*)(corr + e);
  size_t row = e >> 10, col = e & 1023;
  ushort4 o;
  o.x = f2bf(v.x); o.y = f2bf(v.y); o.z = f2bf(v.z); o.w = f2bf(v.w);
  *(ushort4*)((unsigned short*)catb + row * 2048 + 1024 + col) = o;
}

// ------- bf16 MFMA GEMM, 128x128 tile, BK=32, double-buffered (R13) ---------
// Stage tile t+1 into alternate LDS buffer BEFORE computing tile t; single
// barrier per iter (its vmcnt(0) drain lands after compute -> latency hidden).
template <int EPI>
__global__ __launch_bounds__(256) void gemm_bf16(
    const __hip_bfloat16* __restrict__ A, const __hip_bfloat16* __restrict__ Bt,
    const float* __restrict__ bias, void* __restrict__ outp,
    const float* __restrict__ aux0, const float* __restrict__ aux1,
    int M, int N, int K) {
  __shared__ __hip_bfloat16 As[2][128 * 32];
  __shared__ __hip_bfloat16 Bs[2][128 * 32];
  const int tid = threadIdx.x;
  const int lane = tid & 63, wid = tid >> 6;
  const int wr = wid >> 1, wc = wid & 1;
  const int lr = lane & 15, lk = (lane >> 4) * 8;
  const size_t brow = (size_t)blockIdx.y * 128, bcol = (size_t)blockIdx.x * 128;
  f32x4 acc[4][4] = {};
#pragma unroll
  for (int r = 0; r < 2; ++r) {  // prologue: stage K-step 0 into buf 0
    int c = tid + r * 256;
    GLD16(A + (brow + (size_t)(c >> 2)) * K + (c & 3) * 8, As[0] + c * 8);
    GLD16(Bt + (bcol + (size_t)(c >> 2)) * K + (c & 3) * 8, Bs[0] + c * 8);
  }
  __syncthreads();
  int cur = 0;
  for (int k0 = 0; k0 < K; k0 += 32) {
    const int nxt = cur ^ 1;
    if (k0 + 32 < K) {  // issue next-step staging BEFORE compute
#pragma unroll
      for (int r = 0; r < 2; ++r) {
        int c = tid + r * 256;
        GLD16(A + (brow + (size_t)(c >> 2)) * K + k0 + 32 + (c & 3) * 8,
              As[nxt] + c * 8);
        GLD16(Bt + (bcol + (size_t)(c >> 2)) * K + k0 + 32 + (c & 3) * 8,
              Bs[nxt] + c * 8);
      }
    }
    bf16x8 a[4], b[4];
#pragma unroll
    for (int m = 0; m < 4; ++m)
      a[m] = *(const bf16x8*)(As[cur] + (wr * 64 + m * 16 + lr) * 32 + lk);
#pragma unroll
    for (int n = 0; n < 4; ++n)
      b[n] = *(const bf16x8*)(Bs[cur] + (wc * 64 + n * 16 + lr) * 32 + lk);
#pragma unroll
    for (int m = 0; m < 4; ++m)
#pragma unroll
      for (int n = 0; n < 4; ++n)
        acc[m][n] = __builtin_amdgcn_mfma_f32_16x16x32_bf16(a[m], b[n], acc[m][n], 0, 0, 0);
    __syncthreads();  // drains vmcnt(0): prefetch completed during MFMA
    cur = nxt;
  }
  const int r0 = (lane >> 4) * 4, cn = lane & 15;
#pragma unroll
  for (int m = 0; m < 4; ++m)
#pragma unroll
    for (int n = 0; n < 4; ++n) {
      size_t col = bcol + wc * 64 + n * 16 + cn;
      float bv = bias[col];
#pragma unroll
      for (int j = 0; j < 4; ++j) {
        size_t row = brow + wr * 64 + m * 16 + r0 + j;
        float v = acc[m][n][j] + bv;
        if constexpr (EPI == 0) {
          ((__hip_bfloat16*)outp)[row * N + col] = __float2bfloat16(v);
        } else if constexpr (EPI == 1) {
          float g = 1.0f / (1.0f + __expf(-v));
          float val = g * aux0[row * N + col] + aux1[row * N + col];
          ((__hip_bfloat16*)outp)[row * N + col] = __float2bfloat16(val);
        } else {
          ((float*)outp)[row * N + col] = v;
        }
      }
    }
}

// ------- causal flash attention V3i (paired q-tiles, merged hi/lo) ----------
// R9-verified structure/grid/swizzles. Block qtp handles q-tiles qlo=qtp,
// qhi=31-qtp for (b,h)=(z,y). Merged body: K and V fragments are read from
// LDS ONCE per iteration and feed both tiles' MFMAs (DS-pipe is the measured
// bottleneck). lo-tile softmax/ps guarded by block-uniform lo_act.
__global__ __launch_bounds__(256) void attn_kernel(
    const __hip_bfloat16* __restrict__ qkv, float* __restrict__ outp) {
  const int b = blockIdx.z, h = blockIdx.y, qtp = blockIdx.x;
  const int qlo = qtp, qhi = 31 - qtp;
  const int q0lo = qlo * 64, q0hi = qhi * 64;
  __shared__ __hip_bfloat16 ks[2][64 * 64];
  __shared__ __hip_bfloat16 vts[2][64 * 64];  // V^T [dh][kv], swizzled
  __shared__ __hip_bfloat16 qps[8192];        // Q_hi|Q_lo staging -> ps_hi|ps_lo
  const int tid = threadIdx.x, lane = tid & 63, w = tid >> 6;
  const int lr = lane & 15, lg = lane >> 4;
  const int sw = lr & 7;
  const size_t rs = 3072;
  const __hip_bfloat16* qbh = qkv + ((size_t)b * 2048 + q0hi) * rs + h * 64;
  const __hip_bfloat16* qbl = qkv + ((size_t)b * 2048 + q0lo) * rs + h * 64;
  const __hip_bfloat16* kb = qkv + (size_t)b * 2048 * rs + 1024 + h * 64;
  const __hip_bfloat16* vb = qkv + (size_t)b * 2048 * rs + 2048 + h * 64;

  float4 vreg[2];
  // ---- prologue: stage Q_hi/Q_lo/K0 (pre-swizzled src), V0 -> regs
#pragma unroll
  for (int r = 0; r < 2; ++r) {
    int c = tid + r * 256, row = c >> 3, p = c & 7;
    GLD16(qbh + (size_t)row * rs + (p ^ (row & 7)) * 8, qps + c * 8);
    GLD16(qbl + (size_t)row * rs + (p ^ (row & 7)) * 8, qps + 4096 + c * 8);
    GLD16(kb + (size_t)row * rs + (p ^ (row & 7)) * 8, ks[0] + c * 8);
    vreg[r] = *(const float4*)(vb + (size_t)row * rs + p * 8);
  }
  __syncthreads();
  const int qrow = w * 16 + lr;
  const bf16x8 qh0 = *(const bf16x8*)(qps + qrow * 64 + ((lg) ^ (qrow & 7)) * 8);
  const bf16x8 qh1 = *(const bf16x8*)(qps + qrow * 64 + ((4 + lg) ^ (qrow & 7)) * 8);
  const bf16x8 ql0 = *(const bf16x8*)(qps + 4096 + qrow * 64 + ((lg) ^ (qrow & 7)) * 8);
  const bf16x8 ql1 = *(const bf16x8*)(qps + 4096 + qrow * 64 + ((4 + lg) ^ (qrow & 7)) * 8);
  // write V0 (transpose, swizzled)
#pragma unroll
  for (int r = 0; r < 2; ++r) {
    int c = tid + r * 256, row = c >> 3, seg = c & 7;
    const __hip_bfloat16* e8 = (const __hip_bfloat16*)&vreg[r];
#pragma unroll
    for (int i = 0; i < 8; ++i)
      vts[0][(seg * 8 + i) * 64 + (((row >> 3) ^ i ^ seg)) * 8 + (row & 7)] = e8[i];
  }
  __syncthreads();  // Q frags in regs; qps now free for ps

  __hip_bfloat16* psh = qps + w * 1024;         // wave-private, hi tile
  __hip_bfloat16* psl = qps + 4096 + w * 1024;  // wave-private, lo tile
  float m_hi[4] = {-1e30f, -1e30f, -1e30f, -1e30f}, l_hi[4] = {0, 0, 0, 0};
  float m_lo[4] = {-1e30f, -1e30f, -1e30f, -1e30f}, l_lo[4] = {0, 0, 0, 0};
  f32x4 o_hi[4] = {}, o_lo[4] = {};
  int cur = 0;

  for (int kvt = 0; kvt <= qhi; ++kvt) {
    const int nxt = cur ^ 1;
    const bool pf = (kvt < qhi);
    const bool lo_act = (kvt <= qlo);
    if (pf) {  // prefetch next K tile + V rows
      const int kv1 = (kvt + 1) * 64;
#pragma unroll
      for (int r = 0; r < 2; ++r) {
        int c = tid + r * 256, row = c >> 3, p = c & 7;
        GLD16(kb + (size_t)(kv1 + row) * rs + (p ^ (row & 7)) * 8, ks[nxt] + c * 8);
        vreg[r] = *(const float4*)(vb + (size_t)(kv1 + row) * rs + p * 8);
      }
    }
    // ---- QK^T both tiles, K fragments read ONCE
    f32x4 sh[4] = {}, sl[4] = {};
#pragma unroll
    for (int n = 0; n < 4; ++n) {
      const int kr = n * 16 + lr;
      bf16x8 k0f = *(const bf16x8*)(ks[cur] + kr * 64 + ((lg) ^ sw) * 8);
      bf16x8 k1f = *(const bf16x8*)(ks[cur] + kr * 64 + ((4 + lg) ^ sw) * 8);
      sh[n] = __builtin_amdgcn_mfma_f32_16x16x32_bf16(qh0, k0f, sh[n], 0, 0, 0);
      sh[n] = __builtin_amdgcn_mfma_f32_16x16x32_bf16(qh1, k1f, sh[n], 0, 0, 0);
      if (lo_act) {
        sl[n] = __builtin_amdgcn_mfma_f32_16x16x32_bf16(ql0, k0f, sl[n], 0, 0, 0);
        sl[n] = __builtin_amdgcn_mfma_f32_16x16x32_bf16(ql1, k1f, sl[n], 0, 0, 0);
      }
    }
    // ---- softmax hi
    bf16x8 pa_h0, pa_h1, pa_l0, pa_l1;
    {
      const bool diag = (kvt == qhi);
      float p[4][4], mloc[4];
#pragma unroll
      for (int j = 0; j < 4; ++j) {
        float mm = -1e30f;
#pragma unroll
        for (int n = 0; n < 4; ++n) {
          float v = sh[n][j] * 0.125f;
          if (diag && (n * 16 + lr) > (w * 16 + lg * 4 + j)) v = -1e30f;
          p[n][j] = v;
          mm = fmaxf(mm, v);
        }
        mloc[j] = mm;
      }
#pragma unroll
      for (int off = 1; off < 16; off <<= 1)
#pragma unroll
        for (int j = 0; j < 4; ++j)
          mloc[j] = fmaxf(mloc[j], __shfl_xor(mloc[j], off, 16));
      float sc[4], ls[4];
#pragma unroll
      for (int j = 0; j < 4; ++j) {
        float mn = fmaxf(m_hi[j], mloc[j]);
        sc[j] = __expf(m_hi[j] - mn);
        m_hi[j] = mn;
        float s = 0.f;
#pragma unroll
        for (int n = 0; n < 4; ++n) { p[n][j] = __expf(p[n][j] - mn); s += p[n][j]; }
        ls[j] = s;
      }
#pragma unroll
      for (int off = 1; off < 16; off <<= 1)
#pragma unroll
        for (int j = 0; j < 4; ++j) ls[j] += __shfl_xor(ls[j], off, 16);
#pragma unroll
      for (int j = 0; j < 4; ++j) l_hi[j] = l_hi[j] * sc[j] + ls[j];
#pragma unroll
      for (int n = 0; n < 4; ++n)
#pragma unroll
        for (int j = 0; j < 4; ++j) o_hi[n][j] *= sc[j];
#pragma unroll
      for (int n = 0; n < 4; ++n)
#pragma unroll
        for (int j = 0; j < 4; ++j) {
          const int prow = lg * 4 + j;
          const int phys = (n * 2 + (lr >> 3)) ^ (prow & 7);
          psh[prow * 64 + phys * 8 + (lr & 7)] = __float2bfloat16(p[n][j]);
        }
      pa_h0 = *(const bf16x8*)(&psh[lr * 64 + ((lg) ^ sw) * 8]);
      pa_h1 = *(const bf16x8*)(&psh[lr * 64 + ((4 + lg) ^ sw) * 8]);
    }
    // ---- softmax lo (block-uniform guard)
    if (lo_act) {
      const bool diag = (kvt == qlo);
      float p[4][4], mloc[4];
#pragma unroll
      for (int j = 0; j < 4; ++j) {
        float mm = -1e30f;
#pragma unroll
        for (int n = 0; n < 4; ++n) {
          float v = sl[n][j] * 0.125f;
          if (diag && (n * 16 + lr) > (w * 16 + lg * 4 + j)) v = -1e30f;
          p[n][j] = v;
          mm = fmaxf(mm, v);
        }
        mloc[j] = mm;
      }
#pragma unroll
      for (int off = 1; off < 16; off <<= 1)
#pragma unroll
        for (int j = 0; j < 4; ++j)
          mloc[j] = fmaxf(mloc[j], __shfl_xor(mloc[j], off, 16));
      float sc[4], ls[4];
#pragma unroll
      for (int j = 0; j < 4; ++j) {
        float mn = fmaxf(m_lo[j], mloc[j]);
        sc[j] = __expf(m_lo[j] - mn);
        m_lo[j] = mn;
        float s = 0.f;
#pragma unroll
        for (int n = 0; n < 4; ++n) { p[n][j] = __expf(p[n][j] - mn); s += p[n][j]; }
        ls[j] = s;
      }
#pragma unroll
      for (int off = 1; off < 16; off <<= 1)
#pragma unroll
        for (int j = 0; j < 4; ++j) ls[j] += __shfl_xor(ls[j], off, 16);
#pragma unroll
      for (int j = 0; j < 4; ++j) l_lo[j] = l_lo[j] * sc[j] + ls[j];
#pragma unroll
      for (int n = 0; n < 4; ++n)
#pragma unroll
        for (int j = 0; j < 4; ++j) o_lo[n][j] *= sc[j];
#pragma unroll
      for (int n = 0; n < 4; ++n)
#pragma unroll
        for (int j = 0; j < 4; ++j) {
          const int prow = lg * 4 + j;
          const int phys = (n * 2 + (lr >> 3)) ^ (prow & 7);
          psl[prow * 64 + phys * 8 + (lr & 7)] = __float2bfloat16(p[n][j]);
        }
      pa_l0 = *(const bf16x8*)(&psl[lr * 64 + ((lg) ^ sw) * 8]);
      pa_l1 = *(const bf16x8*)(&psl[lr * 64 + ((4 + lg) ^ sw) * 8]);
    }
    // ---- PV both tiles, V fragments read ONCE
#pragma unroll
    for (int n = 0; n < 4; ++n) {
      const int vdh = n * 16 + lr;
      const int swv = (vdh & 7) ^ ((vdh >> 3) & 7);
      bf16x8 v0f = *(const bf16x8*)(vts[cur] + vdh * 64 + ((lg) ^ swv) * 8);
      bf16x8 v1f = *(const bf16x8*)(vts[cur] + vdh * 64 + ((4 + lg) ^ swv) * 8);
      o_hi[n] = __builtin_amdgcn_mfma_f32_16x16x32_bf16(pa_h0, v0f, o_hi[n], 0, 0, 0);
      o_hi[n] = __builtin_amdgcn_mfma_f32_16x16x32_bf16(pa_h1, v1f, o_hi[n], 0, 0, 0);
      if (lo_act) {
        o_lo[n] = __builtin_amdgcn_mfma_f32_16x16x32_bf16(pa_l0, v0f, o_lo[n], 0, 0, 0);
        o_lo[n] = __builtin_amdgcn_mfma_f32_16x16x32_bf16(pa_l1, v1f, o_lo[n], 0, 0, 0);
      }
    }
    // ---- write V(t+1) regs -> vts[nxt] (vmcnt wait lands after compute)
    if (pf) {
#pragma unroll
      for (int r = 0; r < 2; ++r) {
        int c = tid + r * 256, row = c >> 3, seg = c & 7;
        const __hip_bfloat16* e8 = (const __hip_bfloat16*)&vreg[r];
#pragma unroll
        for (int i = 0; i < 8; ++i)
          vts[nxt][(seg * 8 + i) * 64 + (((row >> 3) ^ i ^ seg)) * 8 + (row & 7)] = e8[i];
      }
    }
    __syncthreads();
    cur = nxt;
  }
#pragma unroll
  for (int j = 0; j < 4; ++j) {
    float invh = 1.0f / l_hi[j], invl = 1.0f / l_lo[j];
    size_t rowh = (size_t)b * 2048 + q0hi + w * 16 + lg * 4 + j;
    size_t rowl = (size_t)b * 2048 + q0lo + w * 16 + lg * 4 + j;
#pragma unroll
    for (int n = 0; n < 4; ++n) {
      outp[rowh * 1024 + h * 64 + n * 16 + lr] = o_hi[n][j] * invh;
      outp[rowl * 1024 + h * 64 + n * 16 + lr] = o_lo[n][j] * invl;
    }
  }
}

extern "C" void kernel_launch(void* const* d_in, const int* in_sizes, int n_in,
                              void* d_out, int out_size, void* d_ws, size_t ws_size,
                              hipStream_t stream) {
  const float* x     = (const float*)d_in[0];
  const float* Wqkv0 = (const float*)d_in[1];
  const float* bqkv0 = (const float*)d_in[2];
  const float* Wqkv1 = (const float*)d_in[3];
  const float* bqkv1 = (const float*)d_in[4];
  const float* Wg    = (const float*)d_in[5];
  const float* bg    = (const float*)d_in[6];
  const float* Wo    = (const float*)d_in[7];
  const float* bo    = (const float*)d_in[8];
  float* out = (float*)d_out;

  char* ws = (char*)d_ws;
  __hip_bfloat16* xb   = (__hip_bfloat16*)(ws);              // 8 MB (x_bf16 -> residb -> preout)
  __hip_bfloat16* qkv  = (__hip_bfloat16*)(ws + 8388608);    // 24 MB (qkv0 then qkv1)
  float*          pred = (float*)(ws + 33554432);            // 16 MB
  float*          corr = (float*)(ws + 50331648);            // 16 MB
  __hip_bfloat16* catb = (__hip_bfloat16*)(ws + 67108864);   // 16 MB [pred | corr] bf16
  __hip_bfloat16* Wt0  = (__hip_bfloat16*)(ws + 83886080);   // 6 MB
  __hip_bfloat16* Wt1  = (__hip_bfloat16*)(ws + 90177536);   // 6 MB
  __hip_bfloat16* Wgt  = (__hip_bfloat16*)(ws + 96468992);   // 4 MB
  __hip_bfloat16* Wot  = (__hip_bfloat16*)(ws + 100663296);  // 2 MB  (total ~98 MB)

  dim3 tb(32, 8);
  transpose_cast<<<dim3(3072 / 32, 1024 / 32), tb, 0, stream>>>(Wqkv0, Wt0, 1024, 3072);
  transpose_cast<<<dim3(3072 / 32, 1024 / 32), tb, 0, stream>>>(Wqkv1, Wt1, 1024, 3072);
  transpose_cast<<<dim3(1024 / 32, 2048 / 32), tb, 0, stream>>>(Wg, Wgt, 2048, 1024);
  transpose_cast<<<dim3(1024 / 32, 1024 / 32), tb, 0, stream>>>(Wo, Wot, 1024, 1024);
  cast_f32_bf16<<<4096, 256, 0, stream>>>(x, xb);

  // qkv0 = x @ Wqkv0 + b
  gemm_bf16<0><<<dim3(24, 32), 256, 0, stream>>>(xb, Wt0, bqkv0, (void*)qkv,
                                                 nullptr, nullptr, 4096, 3072, 1024);
  attn_kernel<<<dim3(16, 16, 2), 256, 0, stream>>>(qkv, pred);
  resid_cast<<<4096, 256, 0, stream>>>(x, pred, catb, xb);
  // qkv1 = (x - pred) @ Wqkv1 + b
  gemm_bf16<0><<<dim3(24, 32), 256, 0, stream>>>(xb, Wt1, bqkv1, (void*)qkv,
                                                 nullptr, nullptr, 4096, 3072, 1024);
  attn_kernel<<<dim3(16, 16, 2), 256, 0, stream>>>(qkv, corr);
  corr_cast<<<4096, 256, 0, stream>>>(corr, catb);
  // preout = sigmoid(cat @ Wg + bg) * corr + pred   (into xb)
  gemm_bf16<1><<<dim3(8, 32), 256, 0, stream>>>(catb, Wgt, bg, (void*)xb,
                                                corr, pred, 4096, 1024, 2048);
  // out = preout @ Wo + bo (fp32)
  gemm_bf16<2><<<dim3(8, 32), 256, 0, stream>>>(xb, Wot, bo, (void*)out,
                                                nullptr, nullptr, 4096, 1024, 1024);
}

// Round 15
// 309.324 us; speedup vs baseline: 1.3865x; 1.1449x over previous
//
#include <hip/hip_runtime.h>
#include <hip/hip_bf16.h>

// BoostedCausalAttention: bf16 MFMA pipeline
// B=2 T=2048 D=1024 H=16 DH=64, fp32 in/out, bf16 internal compute.
// R6 589us -> R8 swizzle 475 -> R9 pairing 352.9 (attn 91.3).
// R11 (rev): 8-wave split regressed. R12 (rev): XCD pin: FETCH -5x, dur up.
// R14: GEMM dbuf GOOD (-10us, kept); merged attn body BAD (97.2us, reverted).
// DS model v2: softmax shuffles (32/update, ds_bpermute) + ps round-trip are
//   ~40% of the saturated DS pipe, not just K/V frag reads.
// R15: swapped-operand QK^T — s=mfma(K,Q) transposes S so k is REGISTER-
//   local per lane (q=lr). Softmax: 15 reg-max + 2 shfl (vs 16+16), sum same,
//   +4 shfl sc-broadcast => shuffles 32->8/update; m/l scalar. ps write
//   re-derived (same ^(lr&7) slot swizzle, 2-way). PV unchanged. Attn body
//   otherwise exact R9; GEMM dbuf kept.

typedef __bf16 bf16x8 __attribute__((ext_vector_type(8)));
typedef float f32x4 __attribute__((ext_vector_type(4)));

__device__ __forceinline__ unsigned short f2bf(float f) {
  union { __hip_bfloat16 h; unsigned short u; } cv;
  cv.h = __float2bfloat16(f);
  return cv.u;
}

#define GLD16(gp, lp) __builtin_amdgcn_global_load_lds(                      \
    (const __attribute__((address_space(1))) void*)(gp),                     \
    (__attribute__((address_space(3))) void*)(lp), 16, 0, 0)

// ---------------- transpose + cast: fp32 [R][C] -> bf16 [C][R] --------------
__global__ __launch_bounds__(256) void transpose_cast(
    const float* __restrict__ in, __hip_bfloat16* __restrict__ out, int R, int C) {
  __shared__ float t[32][33];
  int bx = blockIdx.x * 32, by = blockIdx.y * 32;
  int tx = threadIdx.x, ty = threadIdx.y;
#pragma unroll
  for (int i = 0; i < 32; i += 8)
    t[ty + i][tx] = in[(size_t)(by + ty + i) * C + bx + tx];
  __syncthreads();
#pragma unroll
  for (int i = 0; i < 32; i += 8)
    out[(size_t)(bx + ty + i) * R + by + tx] = __float2bfloat16(t[tx][ty + i]);
}

// ---------------- cast x -> bf16 (vec4) ------------------------------------
__global__ __launch_bounds__(256) void cast_f32_bf16(
    const float* __restrict__ in, __hip_bfloat16* __restrict__ out) {
  size_t e = ((size_t)blockIdx.x * blockDim.x + threadIdx.x) * 4;
  float4 v = *(const float4*)(in + e);
  ushort4 o;
  o.x = f2bf(v.x); o.y = f2bf(v.y); o.z = f2bf(v.z); o.w = f2bf(v.w);
  *(ushort4*)((unsigned short*)out + e) = o;
}

// --- catb[:, :1024] = bf16(pred); residb = bf16(x - pred) -------------------
__global__ __launch_bounds__(256) void resid_cast(
    const float* __restrict__ x, const float* __restrict__ pred,
    __hip_bfloat16* __restrict__ catb, __hip_bfloat16* __restrict__ residb) {
  size_t e = ((size_t)blockIdx.x * blockDim.x + threadIdx.x) * 4;
  float4 xv = *(const float4*)(x + e);
  float4 pv = *(const float4*)(pred + e);
  size_t row = e >> 10, col = e & 1023;
  ushort4 pb, rb;
  pb.x = f2bf(pv.x); pb.y = f2bf(pv.y); pb.z = f2bf(pv.z); pb.w = f2bf(pv.w);
  rb.x = f2bf(xv.x - pv.x); rb.y = f2bf(xv.y - pv.y);
  rb.z = f2bf(xv.z - pv.z); rb.w = f2bf(xv.w - pv.w);
  *(ushort4*)((unsigned short*)catb + row * 2048 + col) = pb;
  *(ushort4*)((unsigned short*)residb + e) = rb;
}

// --- catb[:, 1024:] = bf16(corr) --------------------------------------------
__global__ __launch_bounds__(256) void corr_cast(
    const float* __restrict__ corr, __hip_bfloat16* __restrict__ catb) {
  size_t e = ((size_t)blockIdx.x * blockDim.x + threadIdx.x) * 4;
  float4 v = *(const float4*)(corr + e);
  size_t row = e >> 10, col = e & 1023;
  ushort4 o;
  o.x = f2bf(v.x); o.y = f2bf(v.y); o.z = f2bf(v.z); o.w = f2bf(v.w);
  *(ushort4*)((unsigned short*)catb + row * 2048 + 1024 + col) = o;
}

// ------- bf16 MFMA GEMM, 128x128 tile, BK=32, double-buffered (R13) ---------
template <int EPI>
__global__ __launch_bounds__(256) void gemm_bf16(
    const __hip_bfloat16* __restrict__ A, const __hip_bfloat16* __restrict__ Bt,
    const float* __restrict__ bias, void* __restrict__ outp,
    const float* __restrict__ aux0, const float* __restrict__ aux1,
    int M, int N, int K) {
  __shared__ __hip_bfloat16 As[2][128 * 32];
  __shared__ __hip_bfloat16 Bs[2][128 * 32];
  const int tid = threadIdx.x;
  const int lane = tid & 63, wid = tid >> 6;
  const int wr = wid >> 1, wc = wid & 1;
  const int lr = lane & 15, lk = (lane >> 4) * 8;
  const size_t brow = (size_t)blockIdx.y * 128, bcol = (size_t)blockIdx.x * 128;
  f32x4 acc[4][4] = {};
#pragma unroll
  for (int r = 0; r < 2; ++r) {  // prologue: stage K-step 0 into buf 0
    int c = tid + r * 256;
    GLD16(A + (brow + (size_t)(c >> 2)) * K + (c & 3) * 8, As[0] + c * 8);
    GLD16(Bt + (bcol + (size_t)(c >> 2)) * K + (c & 3) * 8, Bs[0] + c * 8);
  }
  __syncthreads();
  int cur = 0;
  for (int k0 = 0; k0 < K; k0 += 32) {
    const int nxt = cur ^ 1;
    if (k0 + 32 < K) {  // issue next-step staging BEFORE compute
#pragma unroll
      for (int r = 0; r < 2; ++r) {
        int c = tid + r * 256;
        GLD16(A + (brow + (size_t)(c >> 2)) * K + k0 + 32 + (c & 3) * 8,
              As[nxt] + c * 8);
        GLD16(Bt + (bcol + (size_t)(c >> 2)) * K + k0 + 32 + (c & 3) * 8,
              Bs[nxt] + c * 8);
      }
    }
    bf16x8 a[4], b[4];
#pragma unroll
    for (int m = 0; m < 4; ++m)
      a[m] = *(const bf16x8*)(As[cur] + (wr * 64 + m * 16 + lr) * 32 + lk);
#pragma unroll
    for (int n = 0; n < 4; ++n)
      b[n] = *(const bf16x8*)(Bs[cur] + (wc * 64 + n * 16 + lr) * 32 + lk);
#pragma unroll
    for (int m = 0; m < 4; ++m)
#pragma unroll
      for (int n = 0; n < 4; ++n)
        acc[m][n] = __builtin_amdgcn_mfma_f32_16x16x32_bf16(a[m], b[n], acc[m][n], 0, 0, 0);
    __syncthreads();  // drains vmcnt(0): prefetch completed during MFMA
    cur = nxt;
  }
  const int r0 = (lane >> 4) * 4, cn = lane & 15;
#pragma unroll
  for (int m = 0; m < 4; ++m)
#pragma unroll
    for (int n = 0; n < 4; ++n) {
      size_t col = bcol + wc * 64 + n * 16 + cn;
      float bv = bias[col];
#pragma unroll
      for (int j = 0; j < 4; ++j) {
        size_t row = brow + wr * 64 + m * 16 + r0 + j;
        float v = acc[m][n][j] + bv;
        if constexpr (EPI == 0) {
          ((__hip_bfloat16*)outp)[row * N + col] = __float2bfloat16(v);
        } else if constexpr (EPI == 1) {
          float g = 1.0f / (1.0f + __expf(-v));
          float val = g * aux0[row * N + col] + aux1[row * N + col];
          ((__hip_bfloat16*)outp)[row * N + col] = __float2bfloat16(val);
        } else {
          ((float*)outp)[row * N + col] = v;
        }
      }
    }
}

// ------- causal flash attention V5 (paired q-tiles, swapped QK^T) -----------
// R9-verified structure/grid/swizzles/staging. Block qtp: q-tiles qlo=qtp,
// qhi=31-qtp for (b,h). Swapped QK^T: s=mfma(K_frag, Q_frag) -> lane holds
// S[q = w*16+lr][k = n*16 + lg*4 + j] (k register-local). Softmax: reg-local
// max/sum + 2 shfl_xor (16,32) + 4-shfl sc broadcast. ps layout [q=lr][k],
// 16B slot swizzled ^(lr&7) (write 2-way, read as before). PV: o layout
// unchanged (P is A-operand).
__global__ __launch_bounds__(256) void attn_kernel(
    const __hip_bfloat16* __restrict__ qkv, float* __restrict__ outp) {
  const int b = blockIdx.z, h = blockIdx.y, qtp = blockIdx.x;
  const int qlo = qtp, qhi = 31 - qtp;
  const int q0lo = qlo * 64, q0hi = qhi * 64;
  __shared__ __hip_bfloat16 ks[2][64 * 64];
  __shared__ __hip_bfloat16 vts[2][64 * 64];  // V^T [dh][kv], swizzled
  __shared__ __hip_bfloat16 qps[8192];        // Q_hi|Q_lo staging -> ps_hi|ps_lo
  const int tid = threadIdx.x, lane = tid & 63, w = tid >> 6;
  const int lr = lane & 15, lg = lane >> 4;
  const int sw = lr & 7;
  const size_t rs = 3072;
  const __hip_bfloat16* qbh = qkv + ((size_t)b * 2048 + q0hi) * rs + h * 64;
  const __hip_bfloat16* qbl = qkv + ((size_t)b * 2048 + q0lo) * rs + h * 64;
  const __hip_bfloat16* kb = qkv + (size_t)b * 2048 * rs + 1024 + h * 64;
  const __hip_bfloat16* vb = qkv + (size_t)b * 2048 * rs + 2048 + h * 64;

  float4 vreg[2];
  // ---- prologue: stage Q_hi/Q_lo/K0 (pre-swizzled src), V0 -> regs
#pragma unroll
  for (int r = 0; r < 2; ++r) {
    int c = tid + r * 256, row = c >> 3, p = c & 7;
    GLD16(qbh + (size_t)row * rs + (p ^ (row & 7)) * 8, qps + c * 8);
    GLD16(qbl + (size_t)row * rs + (p ^ (row & 7)) * 8, qps + 4096 + c * 8);
    GLD16(kb + (size_t)row * rs + (p ^ (row & 7)) * 8, ks[0] + c * 8);
    vreg[r] = *(const float4*)(vb + (size_t)row * rs + p * 8);
  }
  __syncthreads();
  const int qrow = w * 16 + lr;
  const bf16x8 qh0 = *(const bf16x8*)(qps + qrow * 64 + ((lg) ^ (qrow & 7)) * 8);
  const bf16x8 qh1 = *(const bf16x8*)(qps + qrow * 64 + ((4 + lg) ^ (qrow & 7)) * 8);
  const bf16x8 ql0 = *(const bf16x8*)(qps + 4096 + qrow * 64 + ((lg) ^ (qrow & 7)) * 8);
  const bf16x8 ql1 = *(const bf16x8*)(qps + 4096 + qrow * 64 + ((4 + lg) ^ (qrow & 7)) * 8);
  // write V0 (transpose, swizzled)
#pragma unroll
  for (int r = 0; r < 2; ++r) {
    int c = tid + r * 256, row = c >> 3, seg = c & 7;
    const __hip_bfloat16* e8 = (const __hip_bfloat16*)&vreg[r];
#pragma unroll
    for (int i = 0; i < 8; ++i)
      vts[0][(seg * 8 + i) * 64 + (((row >> 3) ^ i ^ seg)) * 8 + (row & 7)] = e8[i];
  }
  __syncthreads();  // Q frags in regs; qps now free for ps

  __hip_bfloat16* psh = qps + w * 1024;         // wave-private, hi tile
  __hip_bfloat16* psl = qps + 4096 + w * 1024;  // wave-private, lo tile
  float m_hi = -1e30f, l_hi = 0.f, m_lo = -1e30f, l_lo = 0.f;
  f32x4 o_hi[4] = {}, o_lo[4] = {};
  int cur = 0;

  // one q-tile update against ks[cur]/vts[cur] (swapped QK^T)
  auto process = [&](const bf16x8& qa0, const bf16x8& qa1, bool diag,
                     float& m_run, float& l_run, f32x4* o, __hip_bfloat16* psw) {
    f32x4 s4[4] = {};
#pragma unroll
    for (int n = 0; n < 4; ++n) {
      const int kr = n * 16 + lr;
      bf16x8 k0f = *(const bf16x8*)(ks[cur] + kr * 64 + ((lg) ^ sw) * 8);
      bf16x8 k1f = *(const bf16x8*)(ks[cur] + kr * 64 + ((4 + lg) ^ sw) * 8);
      s4[n] = __builtin_amdgcn_mfma_f32_16x16x32_bf16(k0f, qa0, s4[n], 0, 0, 0);
      s4[n] = __builtin_amdgcn_mfma_f32_16x16x32_bf16(k1f, qa1, s4[n], 0, 0, 0);
    }
    // lane holds S[q = w*16+lr][k = n*16 + lg*4 + j]
    float p[4][4];
    float mloc = -1e30f;
#pragma unroll
    for (int n = 0; n < 4; ++n)
#pragma unroll
      for (int j = 0; j < 4; ++j) {
        float v = s4[n][j] * 0.125f;
        if (diag && (n * 16 + lg * 4 + j) > (w * 16 + lr)) v = -1e30f;
        p[n][j] = v;
        mloc = fmaxf(mloc, v);
      }
    mloc = fmaxf(mloc, __shfl_xor(mloc, 16));
    mloc = fmaxf(mloc, __shfl_xor(mloc, 32));
    const float mn = fmaxf(m_run, mloc);
    const float sc = __expf(m_run - mn);
    m_run = mn;
    float ls = 0.f;
#pragma unroll
    for (int n = 0; n < 4; ++n)
#pragma unroll
      for (int j = 0; j < 4; ++j) { p[n][j] = __expf(p[n][j] - mn); ls += p[n][j]; }
    ls += __shfl_xor(ls, 16);
    ls += __shfl_xor(ls, 32);
    l_run = l_run * sc + ls;
    float scb[4];
#pragma unroll
    for (int j = 0; j < 4; ++j) scb[j] = __shfl(sc, lg * 4 + j);
#pragma unroll
    for (int n = 0; n < 4; ++n)
#pragma unroll
      for (int j = 0; j < 4; ++j) o[n][j] *= scb[j];
    // P[q=lr][k] -> wave-private swizzled LDS (16B slot ^ (lr&7))
#pragma unroll
    for (int n = 0; n < 4; ++n)
#pragma unroll
      for (int j = 0; j < 4; ++j)
        psw[lr * 64 + ((n * 2 + (lg >> 1)) ^ sw) * 8 + (lg & 1) * 4 + j] =
            __float2bfloat16(p[n][j]);
    bf16x8 pa0 = *(const bf16x8*)(&psw[lr * 64 + ((lg) ^ sw) * 8]);
    bf16x8 pa1 = *(const bf16x8*)(&psw[lr * 64 + ((4 + lg) ^ sw) * 8]);
#pragma unroll
    for (int n = 0; n < 4; ++n) {
      const int vdh = n * 16 + lr;
      const int swv = (vdh & 7) ^ ((vdh >> 3) & 7);
      bf16x8 v0f = *(const bf16x8*)(vts[cur] + vdh * 64 + ((lg) ^ swv) * 8);
      bf16x8 v1f = *(const bf16x8*)(vts[cur] + vdh * 64 + ((4 + lg) ^ swv) * 8);
      o[n] = __builtin_amdgcn_mfma_f32_16x16x32_bf16(pa0, v0f, o[n], 0, 0, 0);
      o[n] = __builtin_amdgcn_mfma_f32_16x16x32_bf16(pa1, v1f, o[n], 0, 0, 0);
    }
  };

  for (int kvt = 0; kvt <= qhi; ++kvt) {
    const int nxt = cur ^ 1;
    const bool pf = (kvt < qhi);
    if (pf) {  // prefetch next K tile + V rows
      const int kv1 = (kvt + 1) * 64;
#pragma unroll
      for (int r = 0; r < 2; ++r) {
        int c = tid + r * 256, row = c >> 3, p = c & 7;
        GLD16(kb + (size_t)(kv1 + row) * rs + (p ^ (row & 7)) * 8, ks[nxt] + c * 8);
        vreg[r] = *(const float4*)(vb + (size_t)(kv1 + row) * rs + p * 8);
      }
    }
    process(qh0, qh1, kvt == qhi, m_hi, l_hi, o_hi, psh);
    if (kvt <= qlo) process(ql0, ql1, kvt == qlo, m_lo, l_lo, o_lo, psl);
    if (pf) {  // write V(t+1) regs -> vts[nxt] (vmcnt wait after compute)
#pragma unroll
      for (int r = 0; r < 2; ++r) {
        int c = tid + r * 256, row = c >> 3, seg = c & 7;
        const __hip_bfloat16* e8 = (const __hip_bfloat16*)&vreg[r];
#pragma unroll
        for (int i = 0; i < 8; ++i)
          vts[nxt][(seg * 8 + i) * 64 + (((row >> 3) ^ i ^ seg)) * 8 + (row & 7)] = e8[i];
      }
    }
    __syncthreads();
    cur = nxt;
  }
  const float linv_h = 1.0f / l_hi, linv_l = 1.0f / l_lo;
#pragma unroll
  for (int j = 0; j < 4; ++j) {
    const float lih = __shfl(linv_h, lg * 4 + j);
    const float lil = __shfl(linv_l, lg * 4 + j);
    size_t rowh = (size_t)b * 2048 + q0hi + w * 16 + lg * 4 + j;
    size_t rowl = (size_t)b * 2048 + q0lo + w * 16 + lg * 4 + j;
#pragma unroll
    for (int n = 0; n < 4; ++n) {
      outp[rowh * 1024 + h * 64 + n * 16 + lr] = o_hi[n][j] * lih;
      outp[rowl * 1024 + h * 64 + n * 16 + lr] = o_lo[n][j] * lil;
    }
  }
}

extern "C" void kernel_launch(void* const* d_in, const int* in_sizes, int n_in,
                              void* d_out, int out_size, void* d_ws, size_t ws_size,
                              hipStream_t stream) {
  const float* x     = (const float*)d_in[0];
  const float* Wqkv0 = (const float*)d_in[1];
  const float* bqkv0 = (const float*)d_in[2];
  const float* Wqkv1 = (const float*)d_in[3];
  const float* bqkv1 = (const float*)d_in[4];
  const float* Wg    = (const float*)d_in[5];
  const float* bg    = (const float*)d_in[6];
  const float* Wo    = (const float*)d_in[7];
  const float* bo    = (const float*)d_in[8];
  float* out = (float*)d_out;

  char* ws = (char*)d_ws;
  __hip_bfloat16* xb   = (__hip_bfloat16*)(ws);              // 8 MB (x_bf16 -> residb -> preout)
  __hip_bfloat16* qkv  = (__hip_bfloat16*)(ws + 8388608);    // 24 MB (qkv0 then qkv1)
  float*          pred = (float*)(ws + 33554432);            // 16 MB
  float*          corr = (float*)(ws + 50331648);            // 16 MB
  __hip_bfloat16* catb = (__hip_bfloat16*)(ws + 67108864);   // 16 MB [pred | corr] bf16
  __hip_bfloat16* Wt0  = (__hip_bfloat16*)(ws + 83886080);   // 6 MB
  __hip_bfloat16* Wt1  = (__hip_bfloat16*)(ws + 90177536);   // 6 MB
  __hip_bfloat16* Wgt  = (__hip_bfloat16*)(ws + 96468992);   // 4 MB
  __hip_bfloat16* Wot  = (__hip_bfloat16*)(ws + 100663296);  // 2 MB  (total ~98 MB)

  dim3 tb(32, 8);
  transpose_cast<<<dim3(3072 / 32, 1024 / 32), tb, 0, stream>>>(Wqkv0, Wt0, 1024, 3072);
  transpose_cast<<<dim3(3072 / 32, 1024 / 32), tb, 0, stream>>>(Wqkv1, Wt1, 1024, 3072);
  transpose_cast<<<dim3(1024 / 32, 2048 / 32), tb, 0, stream>>>(Wg, Wgt, 2048, 1024);
  transpose_cast<<<dim3(1024 / 32, 1024 / 32), tb, 0, stream>>>(Wo, Wot, 1024, 1024);
  cast_f32_bf16<<<4096, 256, 0, stream>>>(x, xb);

  // qkv0 = x @ Wqkv0 + b
  gemm_bf16<0><<<dim3(24, 32), 256, 0, stream>>>(xb, Wt0, bqkv0, (void*)qkv,
                                                 nullptr, nullptr, 4096, 3072, 1024);
  attn_kernel<<<dim3(16, 16, 2), 256, 0, stream>>>(qkv, pred);
  resid_cast<<<4096, 256, 0, stream>>>(x, pred, catb, xb);
  // qkv1 = (x - pred) @ Wqkv1 + b
  gemm_bf16<0><<<dim3(24, 32), 256, 0, stream>>>(xb, Wt1, bqkv1, (void*)qkv,
                                                 nullptr, nullptr, 4096, 3072, 1024);
  attn_kernel<<<dim3(16, 16, 2), 256, 0, stream>>>(qkv, corr);
  corr_cast<<<4096, 256, 0, stream>>>(corr, catb);
  // preout = sigmoid(cat @ Wg + bg) * corr + pred   (into xb)
  gemm_bf16<1><<<dim3(8, 32), 256, 0, stream>>>(catb, Wgt, bg, (void*)xb,
                                                corr, pred, 4096, 1024, 2048);
  // out = preout @ Wo + bo (fp32)
  gemm_bf16<2><<<dim3(8, 32), 256, 0, stream>>>(xb, Wot, bo, (void*)out,
                                                nullptr, nullptr, 4096, 1024, 1024);
}